// Round 14
// baseline (109.581 us; speedup 1.0000x reference)
//
#include <hip/hip_runtime.h>
#include <hip/hip_bf16.h>

// N=2048, D_IN=128, H=256, D_EMB=64
// inputs: 0:x 1:adj(unused) 2:W0 3:b0 4:W1 5:b1 6:W2 7:b2 8:temp 9:theta
// d_out: out[2048*128] then adj_wts[2048*2048]
//
// R14: k1 reverted to the proven 8-wave/128-block form (R13's 256-block k1
// overran row space and corrupted xlT_bf). Single change vs R12:
// k2f __launch_bounds__(256,4) -> 4 blocks/CU -> 1024-block grid is ONE
// resident batch (was ~3 blocks/CU = 1.33 batches with an idle-machine tail).

typedef short bf16x8 __attribute__((ext_vector_type(8)));
typedef float f32x4 __attribute__((ext_vector_type(4)));

__device__ __forceinline__ unsigned short f2bf(float f) {
    unsigned u = __float_as_uint(f);
    unsigned r = u + 0x7fffu + ((u >> 16) & 1u);
    return (unsigned short)(r >> 16);
}

// pack 8 f32 -> bf16x8 with round-half-up
__device__ __forceinline__ bf16x8 pack_rne8(const float* p) {
    union { unsigned u[4]; bf16x8 v; } r;
    #pragma unroll
    for (int i = 0; i < 4; ++i) {
        unsigned lo = __float_as_uint(p[2 * i]) + 0x8000u;
        unsigned hi = __float_as_uint(p[2 * i + 1]) + 0x8000u;
        r.u[i] = __builtin_amdgcn_perm(hi, lo, 0x07060302u);
    }
    return r.v;
}

// truncation-pack (for the already-rounded P tile in k2)
__device__ __forceinline__ bf16x8 pack_bf8(const float* p) {
    union { unsigned u[4]; bf16x8 v; } r;
    #pragma unroll
    for (int i = 0; i < 4; ++i)
        r.u[i] = __builtin_amdgcn_perm(__float_as_uint(p[2 * i + 1]),
                                       __float_as_uint(p[2 * i]), 0x07060302u);
    return r.v;
}

// ---------------- Kernel 1: fused MLP via MFMA, 8 waves ----------------
// grid 128 x 512 thr. Block: 16 rows. GEMM0 split over 8 waves; then waves 0-3
// run GEMM1 while waves 4-7 run GEMM2 concurrently.
__global__ __launch_bounds__(512, 2) void k1_mfma(
    const float* __restrict__ x,
    const float* __restrict__ W0, const float* __restrict__ b0,
    const float* __restrict__ W1, const float* __restrict__ b1,
    const float* __restrict__ W2, const float* __restrict__ b2,
    unsigned short* __restrict__ emb_bf,   // [2048][64] bf16
    unsigned short* __restrict__ xlT_bf,   // [128][2048] bf16
    float* __restrict__ sq)                // [2048]
{
    constexpr int LDO = 264;               // out_x LDS stride (bf16 elems)
    __shared__ unsigned short oxb[16 * LDO];
    __shared__ float sqs[4][16];

    const int t = threadIdx.x;
    const int lane = t & 63;
    const int w = t >> 6;      // wave 0..7
    const int m = lane & 15;
    const int q = lane >> 4;
    const int i0 = blockIdx.x * 16;

    // A-fragments of x (rows i0+m, K=128)
    bf16x8 ax[4];
    #pragma unroll
    for (int kb = 0; kb < 4; ++kb) {
        float xf[8];
        *(f32x4*)&xf[0] = *(const f32x4*)(x + (size_t)(i0 + m) * 128 + kb * 32 + q * 8);
        *(f32x4*)&xf[4] = *(const f32x4*)(x + (size_t)(i0 + m) * 128 + kb * 32 + q * 8 + 4);
        ax[kb] = pack_rne8(xf);
    }

    // prefetch phase-2 weight fragments (barrier-independent)
    bf16x8 wp[8];
    float bias2 = 0.f;
    if (w < 4) {
        const int h = w * 16 + m;
        bias2 = b1[h];
        #pragma unroll
        for (int kb = 0; kb < 8; ++kb) {
            float wf[8];
            #pragma unroll
            for (int j = 0; j < 8; ++j) wf[j] = W1[(size_t)(kb * 32 + q * 8 + j) * 64 + h];
            wp[kb] = pack_rne8(wf);
        }
    } else {
        const int w2 = w - 4;
        #pragma unroll
        for (int hh = 0; hh < 2; ++hh) {
            const int c = (w2 * 2 + hh) * 16 + m;
            #pragma unroll
            for (int kb = 0; kb < 4; ++kb) {
                float wf[8];
                #pragma unroll
                for (int j = 0; j < 8; ++j) wf[j] = W2[(size_t)(kb * 32 + q * 8 + j) * 128 + c];
                wp[hh * 4 + kb] = pack_rne8(wf);
            }
        }
    }

    // GEMM0: out_x = relu(x @ W0 + b0), wave w covers cols w*32..w*32+31
    #pragma unroll
    for (int hh = 0; hh < 2; ++hh) {
        const int h = (w * 2 + hh) * 16 + m;
        float bb = b0[h];
        f32x4 acc = {bb, bb, bb, bb};
        #pragma unroll
        for (int kb = 0; kb < 4; ++kb) {
            float wf[8];
            #pragma unroll
            for (int j = 0; j < 8; ++j) wf[j] = W0[(size_t)(kb * 32 + q * 8 + j) * 256 + h];
            acc = __builtin_amdgcn_mfma_f32_16x16x32_bf16(ax[kb], pack_rne8(wf), acc, 0, 0, 0);
        }
        #pragma unroll
        for (int r = 0; r < 4; ++r)
            oxb[(q * 4 + r) * LDO + h] = f2bf(fmaxf(acc[r], 0.0f));
    }
    __syncthreads();

    if (w < 4) {
        // GEMM1 (waves 0-3): emb = relu(out_x @ W1 + b1), cols w*16..w*16+15
        const int h = w * 16 + m;
        f32x4 acc = {bias2, bias2, bias2, bias2};
        #pragma unroll
        for (int kb = 0; kb < 8; ++kb) {
            bf16x8 af = *(const bf16x8*)(&oxb[m * LDO + kb * 32 + q * 8]);
            acc = __builtin_amdgcn_mfma_f32_16x16x32_bf16(af, wp[kb], acc, 0, 0, 0);
        }
        float s2[4];
        #pragma unroll
        for (int r = 0; r < 4; ++r) {
            float e = fmaxf(acc[r], 0.0f);
            emb_bf[(size_t)(i0 + q * 4 + r) * 64 + h] = f2bf(e);
            s2[r] = e * e;
        }
        #pragma unroll
        for (int r = 0; r < 4; ++r) {
            float v = s2[r];
            v += __shfl_xor(v, 1);
            v += __shfl_xor(v, 2);
            v += __shfl_xor(v, 4);
            v += __shfl_xor(v, 8);
            if (m == 0) sqs[w][q * 4 + r] = v;
        }
    } else {
        // GEMM2 (waves 4-7): x_last = x @ W2 + b2, cols (w-4)*32..+31
        const int w2 = w - 4;
        #pragma unroll
        for (int hh = 0; hh < 2; ++hh) {
            const int c = (w2 * 2 + hh) * 16 + m;
            float bb = b2[c];
            f32x4 acc = {bb, bb, bb, bb};
            #pragma unroll
            for (int kb = 0; kb < 4; ++kb)
                acc = __builtin_amdgcn_mfma_f32_16x16x32_bf16(ax[kb], wp[hh * 4 + kb], acc, 0, 0, 0);
            uint2 pk;
            pk.x = (unsigned)f2bf(acc[0]) | ((unsigned)f2bf(acc[1]) << 16);
            pk.y = (unsigned)f2bf(acc[2]) | ((unsigned)f2bf(acc[3]) << 16);
            *(uint2*)(&xlT_bf[(size_t)c * 2048 + i0 + q * 4]) = pk;
        }
    }
    __syncthreads();
    if (t < 16)
        sq[i0 + t] = sqs[0][t] + sqs[1][t] + sqs[2][t] + sqs[3][t];
}

// ---------------- Kernel 2: fused adjacency + A@x_last (partial stores) ----------------
// grid (128 i-tiles, 8 j-strips) x 256 thr. Block: 16 rows x 256 cols in 2 iters.
// __launch_bounds__(256,4): VGPR<=128 -> 4 blocks/CU -> single resident batch.
__global__ __launch_bounds__(256, 4) void k2f(
    const unsigned short* __restrict__ emb_bf,
    const unsigned short* __restrict__ xlT_bf,
    const float* __restrict__ sq,
    const float* __restrict__ tempp, const float* __restrict__ thetap,
    float* __restrict__ adjw,      // [2048][2048] f32
    float* __restrict__ outPart,   // [8][128][1024] float2
    float* __restrict__ degPart)   // [8][2048]
{
    constexpr int LDP = 132;
    __shared__ float Pt[2][16 * LDP];
    __shared__ float degS[4][16];

    const int t = threadIdx.x;
    const int lane = t & 63;
    const int w = t >> 6;
    const int m = lane & 15;
    const int q = lane >> 4;
    const int i0 = blockIdx.x * 16;
    const int bj = blockIdx.y;
    const int jstrip0 = bj * 256;
    const float scale = 1.0f + tempp[0];
    const float bias = 5.0f + thetap[0];

    bf16x8 a0 = *(const bf16x8*)(emb_bf + (size_t)(i0 + m) * 64 + q * 8);
    bf16x8 a1 = *(const bf16x8*)(emb_bf + (size_t)(i0 + m) * 64 + 32 + q * 8);
    float sqIr[4];
    #pragma unroll
    for (int r = 0; r < 4; ++r) sqIr[r] = sq[i0 + q * 4 + r];

    f32x4 accO0 = {0.f, 0.f, 0.f, 0.f};
    f32x4 accO1 = {0.f, 0.f, 0.f, 0.f};
    float dega[4] = {0.f, 0.f, 0.f, 0.f};
    const int cg = w * 32;

    #pragma unroll
    for (int jt = 0; jt < 2; ++jt) {
        const int j0 = jstrip0 + jt * 128;
        float* P = &Pt[jt][0];

        // prefetch AX B-fragments (xlT) — independent of the P tile
        bf16x8 xb[8];
        #pragma unroll
        for (int s = 0; s < 4; ++s) {
            const int k = j0 + s * 32 + q * 8;
            xb[2 * s]     = *(const bf16x8*)(xlT_bf + (size_t)(cg + m) * 2048 + k);
            xb[2 * s + 1] = *(const bf16x8*)(xlT_bf + (size_t)(cg + 16 + m) * 2048 + k);
        }

        // S phase: wave w computes cols 32w..32w+31
        #pragma unroll
        for (int s = 0; s < 2; ++s) {
            const int col = (w * 2 + s) * 16 + m;
            const unsigned short* ebj = emb_bf + (size_t)(j0 + col) * 64;
            bf16x8 b0 = *(const bf16x8*)(ebj + q * 8);
            bf16x8 b1 = *(const bf16x8*)(ebj + 32 + q * 8);
            f32x4 S = {0.f, 0.f, 0.f, 0.f};
            S = __builtin_amdgcn_mfma_f32_16x16x32_bf16(a0, b0, S, 0, 0, 0);
            S = __builtin_amdgcn_mfma_f32_16x16x32_bf16(a1, b1, S, 0, 0, 0);

            const float csqJ = sq[j0 + col];
            const int gcol = j0 + col;
            #pragma unroll
            for (int r = 0; r < 4; ++r) {
                int grow = i0 + q * 4 + r;
                float dist = 2.0f * S[r] - sqIr[r] - csqJ;
                float z = scale * dist + bias;
                float p = __builtin_amdgcn_rcpf(1.0f + __expf(-z));
                if (grow == gcol) p += 1.0f;
                dega[r] += p;
                P[(q * 4 + r) * LDP + col] = p;
            }
        }
        __syncthreads();

        // adjw store: 32 consecutive lanes x 16B = full 128B lines per instr
        {
            int row = t >> 5;            // 0..7
            int c0 = (t & 31) * 4;       // f32 col 0..124
            f32x4 v0 = *(const f32x4*)(&P[row * LDP + c0]);
            f32x4 v1 = *(const f32x4*)(&P[(row + 8) * LDP + c0]);
            *(f32x4*)(adjw + (size_t)(i0 + row) * 2048 + j0 + c0) = v0;
            *(f32x4*)(adjw + (size_t)(i0 + row + 8) * 2048 + j0 + c0) = v1;
        }

        // AX: acc += P(16x128) @ xlT (prefetched), K=128
        #pragma unroll
        for (int s = 0; s < 4; ++s) {
            float af[8];
            *(f32x4*)(&af[0]) = *(const f32x4*)(&P[m * LDP + s * 32 + q * 8]);
            *(f32x4*)(&af[4]) = *(const f32x4*)(&P[m * LDP + s * 32 + q * 8 + 4]);
            bf16x8 aa = pack_bf8(af);
            accO0 = __builtin_amdgcn_mfma_f32_16x16x32_bf16(aa, xb[2 * s], accO0, 0, 0, 0);
            accO1 = __builtin_amdgcn_mfma_f32_16x16x32_bf16(aa, xb[2 * s + 1], accO1, 0, 0, 0);
        }
    }

    // deg partial: reduce over m-lanes, combine 4 waves via LDS, plain store
    #pragma unroll
    for (int r = 0; r < 4; ++r) {
        float v = dega[r];
        v += __shfl_xor(v, 1);
        v += __shfl_xor(v, 2);
        v += __shfl_xor(v, 4);
        v += __shfl_xor(v, 8);
        if (m == 0) degS[w][q * 4 + r] = v;
    }
    __syncthreads();
    if (t < 16)
        degPart[bj * 2048 + i0 + t] =
            degS[0][t] + degS[1][t] + degS[2][t] + degS[3][t];

    // out partial: float2-packed full-line stores
    float2* opf2 = (float2*)outPart + ((size_t)bj * 128 + blockIdx.x) * 1024;
    #pragma unroll
    for (int r = 0; r < 4; ++r) {
        float2 pk;
        pk.x = accO0[r];
        pk.y = accO1[r];
        opf2[((q * 4 + r) * 4 + w) * 16 + m] = pk;
    }
}

// ---------------- Kernel 3: out = relu(sum_p outPart / sum_p degPart) ----------------
__global__ __launch_bounds__(256) void k3_fin(
    const float* __restrict__ outPart, const float* __restrict__ degPart,
    float* __restrict__ out)
{
    int gid = blockIdx.x * 256 + threadIdx.x;  // 131072 = 2048 rows * 64 (w,m)
    int i = gid >> 6;
    int wm = gid & 63;
    int w = wm >> 4, m = wm & 15;
    int tile = i >> 4, rit = i & 15;
    size_t base = (size_t)tile * 2048 + (size_t)((rit * 4 + w) * 16 + m) * 2;
    float s0 = 0.f, s1 = 0.f, d = 0.f;
    #pragma unroll
    for (int p = 0; p < 8; ++p) {
        const float* src = outPart + (size_t)p * 262144 + base;
        s0 += src[0];
        s1 += src[1];
        d += degPart[p * 2048 + i];
    }
    float dinv = 1.0f / d;
    out[(size_t)i * 128 + w * 32 + m] = fmaxf(s0 * dinv, 0.f);
    out[(size_t)i * 128 + w * 32 + 16 + m] = fmaxf(s1 * dinv, 0.f);
}

extern "C" void kernel_launch(void* const* d_in, const int* in_sizes, int n_in,
                              void* d_out, int out_size, void* d_ws, size_t ws_size,
                              hipStream_t stream) {
    const float* x     = (const float*)d_in[0];
    const float* W0    = (const float*)d_in[2];
    const float* b0    = (const float*)d_in[3];
    const float* W1    = (const float*)d_in[4];
    const float* b1    = (const float*)d_in[5];
    const float* W2    = (const float*)d_in[6];
    const float* b2    = (const float*)d_in[7];
    const float* temp  = (const float*)d_in[8];
    const float* theta = (const float*)d_in[9];

    char* ws = (char*)d_ws;
    unsigned short* emb_bf = (unsigned short*)(ws);            // 262144 B
    unsigned short* xlT_bf = (unsigned short*)(ws + 262144);   // 524288 B
    float* sq      = (float*)(ws + 786432);                    //   8192 B
    float* degPart = (float*)(ws + 794624);                    //  65536 B
    float* outPart = (float*)(ws + 860160);                    // 8 MiB

    float* out  = (float*)d_out;              // [2048*128]
    float* adjw = (float*)d_out + 262144;     // [2048*2048]

    k1_mfma<<<128, 512, 0, stream>>>(x, W0, b0, W1, b1, W2, b2,
                                     emb_bf, xlT_bf, sq);
    k2f<<<dim3(128, 8), 256, 0, stream>>>(emb_bf, xlT_bf, sq, temp, theta,
                                          adjw, outPart, degPart);
    k3_fin<<<512, 256, 0, stream>>>(outPart, degPart, out);
}

// Round 15
// 109.291 us; speedup vs baseline: 1.0027x; 1.0027x over previous
//
#include <hip/hip_runtime.h>
#include <hip/hip_bf16.h>

// N=2048, D_IN=128, H=256, D_EMB=64
// inputs: 0:x 1:adj(unused) 2:W0 3:b0 4:W1 5:b1 6:W2 7:b2 8:temp 9:theta
// d_out: out[2048*128] then adj_wts[2048*2048]
//
// R15: k0_pack pre-packs W0/W1/W2 into fragment-contiguous bf16 so k1's
// weight loads become ONE coalesced 16B vector load per fragment (was 8
// scalar loads at 1KB stride -> 4-8 L1 transactions per wave instruction,
// ~8.4M scalar loads total = the hidden ~20us in k1). k2f/k3 unchanged.

typedef short bf16x8 __attribute__((ext_vector_type(8)));
typedef float f32x4 __attribute__((ext_vector_type(4)));

__device__ __forceinline__ unsigned short f2bf(float f) {
    unsigned u = __float_as_uint(f);
    unsigned r = u + 0x7fffu + ((u >> 16) & 1u);
    return (unsigned short)(r >> 16);
}

// pack 8 f32 -> bf16x8 with round-half-up
__device__ __forceinline__ bf16x8 pack_rne8(const float* p) {
    union { unsigned u[4]; bf16x8 v; } r;
    #pragma unroll
    for (int i = 0; i < 4; ++i) {
        unsigned lo = __float_as_uint(p[2 * i]) + 0x8000u;
        unsigned hi = __float_as_uint(p[2 * i + 1]) + 0x8000u;
        r.u[i] = __builtin_amdgcn_perm(hi, lo, 0x07060302u);
    }
    return r.v;
}

// truncation-pack (for the already-rounded P tile in k2)
__device__ __forceinline__ bf16x8 pack_bf8(const float* p) {
    union { unsigned u[4]; bf16x8 v; } r;
    #pragma unroll
    for (int i = 0; i < 4; ++i)
        r.u[i] = __builtin_amdgcn_perm(__float_as_uint(p[2 * i + 1]),
                                       __float_as_uint(p[2 * i]), 0x07060302u);
    return r.v;
}

// ---------------- Kernel 0: pack weights into fragment-contiguous bf16 ----------------
// Layouts (slot -> 8 contiguous bf16 = one lane's B-fragment):
//   W0P[((cg*4+kb)*64 + lane)*8 + j] = bf16(W0[(kb*32+q*8+j)*256 + cg*16+m])   cg:16 kb:4
//   W1P[((cg*8+kb)*64 + lane)*8 + j] = bf16(W1[(kb*32+q*8+j)*64  + cg*16+m])   cg:4  kb:8
//   W2P[((cg*4+kb)*64 + lane)*8 + j] = bf16(W2[(kb*32+q*8+j)*128 + cg*16+m])   cg:8  kb:4
__global__ __launch_bounds__(256) void k0_pack(
    const float* __restrict__ W0, const float* __restrict__ W1,
    const float* __restrict__ W2,
    unsigned short* __restrict__ W0P, unsigned short* __restrict__ W1P,
    unsigned short* __restrict__ W2P)
{
    const int b = blockIdx.x;
    const int tid = threadIdx.x;
    float wf[8];
    if (b < 16) {                       // W0: 4096 slots
        int s = b * 256 + tid;
        int lane = s & 63, kb = (s >> 6) & 3, cg = s >> 8;
        int q = lane >> 4, m = lane & 15;
        #pragma unroll
        for (int j = 0; j < 8; ++j)
            wf[j] = W0[(size_t)(kb * 32 + q * 8 + j) * 256 + cg * 16 + m];
        *(bf16x8*)(W0P + (size_t)s * 8) = pack_rne8(wf);
    } else if (b < 24) {                // W1: 2048 slots
        int s = (b - 16) * 256 + tid;
        int lane = s & 63, kb = (s >> 6) & 7, cg = s >> 9;
        int q = lane >> 4, m = lane & 15;
        #pragma unroll
        for (int j = 0; j < 8; ++j)
            wf[j] = W1[(size_t)(kb * 32 + q * 8 + j) * 64 + cg * 16 + m];
        *(bf16x8*)(W1P + (size_t)s * 8) = pack_rne8(wf);
    } else {                            // W2: 2048 slots
        int s = (b - 24) * 256 + tid;
        int lane = s & 63, kb = (s >> 6) & 3, cg = s >> 8;
        int q = lane >> 4, m = lane & 15;
        #pragma unroll
        for (int j = 0; j < 8; ++j)
            wf[j] = W2[(size_t)(kb * 32 + q * 8 + j) * 128 + cg * 16 + m];
        *(bf16x8*)(W2P + (size_t)s * 8) = pack_rne8(wf);
    }
}

// ---------------- Kernel 1: fused MLP via MFMA, 8 waves ----------------
// grid 128 x 512 thr. Block: 16 rows. GEMM0 split over 8 waves; then waves 0-3
// run GEMM1 while waves 4-7 run GEMM2 concurrently. ALL weight fragments are
// single coalesced bf16x8 loads from the packed layouts.
__global__ __launch_bounds__(512, 2) void k1_mfma(
    const float* __restrict__ x,
    const unsigned short* __restrict__ W0P, const float* __restrict__ b0,
    const unsigned short* __restrict__ W1P, const float* __restrict__ b1,
    const unsigned short* __restrict__ W2P, const float* __restrict__ b2,
    unsigned short* __restrict__ emb_bf,   // [2048][64] bf16
    unsigned short* __restrict__ xlT_bf,   // [128][2048] bf16
    float* __restrict__ sq)                // [2048]
{
    constexpr int LDO = 264;               // out_x LDS stride (bf16 elems)
    __shared__ unsigned short oxb[16 * LDO];
    __shared__ float sqs[4][16];

    const int t = threadIdx.x;
    const int lane = t & 63;
    const int w = t >> 6;      // wave 0..7
    const int m = lane & 15;
    const int q = lane >> 4;
    const int i0 = blockIdx.x * 16;

    // A-fragments of x (rows i0+m, K=128)
    bf16x8 ax[4];
    #pragma unroll
    for (int kb = 0; kb < 4; ++kb) {
        float xf[8];
        *(f32x4*)&xf[0] = *(const f32x4*)(x + (size_t)(i0 + m) * 128 + kb * 32 + q * 8);
        *(f32x4*)&xf[4] = *(const f32x4*)(x + (size_t)(i0 + m) * 128 + kb * 32 + q * 8 + 4);
        ax[kb] = pack_rne8(xf);
    }

    // prefetch phase-2 weight fragments (coalesced, barrier-independent)
    bf16x8 wp[8];
    float bias2 = 0.f;
    if (w < 4) {
        bias2 = b1[w * 16 + m];
        #pragma unroll
        for (int kb = 0; kb < 8; ++kb)
            wp[kb] = *(const bf16x8*)(W1P + (size_t)((w * 8 + kb) * 64 + lane) * 8);
    } else {
        const int w2 = w - 4;
        #pragma unroll
        for (int hh = 0; hh < 2; ++hh) {
            const int cg = w2 * 2 + hh;
            #pragma unroll
            for (int kb = 0; kb < 4; ++kb)
                wp[hh * 4 + kb] = *(const bf16x8*)(W2P + (size_t)((cg * 4 + kb) * 64 + lane) * 8);
        }
    }

    // GEMM0: out_x = relu(x @ W0 + b0), wave w covers cols w*32..w*32+31
    #pragma unroll
    for (int hh = 0; hh < 2; ++hh) {
        const int cg0 = w * 2 + hh;
        const int h = cg0 * 16 + m;
        float bb = b0[h];
        f32x4 acc = {bb, bb, bb, bb};
        #pragma unroll
        for (int kb = 0; kb < 4; ++kb) {
            bf16x8 bfr = *(const bf16x8*)(W0P + (size_t)((cg0 * 4 + kb) * 64 + lane) * 8);
            acc = __builtin_amdgcn_mfma_f32_16x16x32_bf16(ax[kb], bfr, acc, 0, 0, 0);
        }
        #pragma unroll
        for (int r = 0; r < 4; ++r)
            oxb[(q * 4 + r) * LDO + h] = f2bf(fmaxf(acc[r], 0.0f));
    }
    __syncthreads();

    if (w < 4) {
        // GEMM1 (waves 0-3): emb = relu(out_x @ W1 + b1), cols w*16..w*16+15
        const int h = w * 16 + m;
        f32x4 acc = {bias2, bias2, bias2, bias2};
        #pragma unroll
        for (int kb = 0; kb < 8; ++kb) {
            bf16x8 af = *(const bf16x8*)(&oxb[m * LDO + kb * 32 + q * 8]);
            acc = __builtin_amdgcn_mfma_f32_16x16x32_bf16(af, wp[kb], acc, 0, 0, 0);
        }
        float s2[4];
        #pragma unroll
        for (int r = 0; r < 4; ++r) {
            float e = fmaxf(acc[r], 0.0f);
            emb_bf[(size_t)(i0 + q * 4 + r) * 64 + h] = f2bf(e);
            s2[r] = e * e;
        }
        #pragma unroll
        for (int r = 0; r < 4; ++r) {
            float v = s2[r];
            v += __shfl_xor(v, 1);
            v += __shfl_xor(v, 2);
            v += __shfl_xor(v, 4);
            v += __shfl_xor(v, 8);
            if (m == 0) sqs[w][q * 4 + r] = v;
        }
    } else {
        // GEMM2 (waves 4-7): x_last = x @ W2 + b2, cols (w-4)*32..+31
        const int w2 = w - 4;
        #pragma unroll
        for (int hh = 0; hh < 2; ++hh) {
            const int c = (w2 * 2 + hh) * 16 + m;
            float bb = b2[c];
            f32x4 acc = {bb, bb, bb, bb};
            #pragma unroll
            for (int kb = 0; kb < 4; ++kb)
                acc = __builtin_amdgcn_mfma_f32_16x16x32_bf16(ax[kb], wp[hh * 4 + kb], acc, 0, 0, 0);
            uint2 pk;
            pk.x = (unsigned)f2bf(acc[0]) | ((unsigned)f2bf(acc[1]) << 16);
            pk.y = (unsigned)f2bf(acc[2]) | ((unsigned)f2bf(acc[3]) << 16);
            *(uint2*)(&xlT_bf[(size_t)c * 2048 + i0 + q * 4]) = pk;
        }
    }
    __syncthreads();
    if (t < 16)
        sq[i0 + t] = sqs[0][t] + sqs[1][t] + sqs[2][t] + sqs[3][t];
}

// ---------------- Kernel 2: fused adjacency + A@x_last (partial stores) ----------------
// grid (128 i-tiles, 8 j-strips) x 256 thr. Unchanged from R14.
__global__ __launch_bounds__(256, 4) void k2f(
    const unsigned short* __restrict__ emb_bf,
    const unsigned short* __restrict__ xlT_bf,
    const float* __restrict__ sq,
    const float* __restrict__ tempp, const float* __restrict__ thetap,
    float* __restrict__ adjw,      // [2048][2048] f32
    float* __restrict__ outPart,   // [8][128][1024] float2
    float* __restrict__ degPart)   // [8][2048]
{
    constexpr int LDP = 132;
    __shared__ float Pt[2][16 * LDP];
    __shared__ float degS[4][16];

    const int t = threadIdx.x;
    const int lane = t & 63;
    const int w = t >> 6;
    const int m = lane & 15;
    const int q = lane >> 4;
    const int i0 = blockIdx.x * 16;
    const int bj = blockIdx.y;
    const int jstrip0 = bj * 256;
    const float scale = 1.0f + tempp[0];
    const float bias = 5.0f + thetap[0];

    bf16x8 a0 = *(const bf16x8*)(emb_bf + (size_t)(i0 + m) * 64 + q * 8);
    bf16x8 a1 = *(const bf16x8*)(emb_bf + (size_t)(i0 + m) * 64 + 32 + q * 8);
    float sqIr[4];
    #pragma unroll
    for (int r = 0; r < 4; ++r) sqIr[r] = sq[i0 + q * 4 + r];

    f32x4 accO0 = {0.f, 0.f, 0.f, 0.f};
    f32x4 accO1 = {0.f, 0.f, 0.f, 0.f};
    float dega[4] = {0.f, 0.f, 0.f, 0.f};
    const int cg = w * 32;

    #pragma unroll
    for (int jt = 0; jt < 2; ++jt) {
        const int j0 = jstrip0 + jt * 128;
        float* P = &Pt[jt][0];

        // prefetch AX B-fragments (xlT) — independent of the P tile
        bf16x8 xb[8];
        #pragma unroll
        for (int s = 0; s < 4; ++s) {
            const int k = j0 + s * 32 + q * 8;
            xb[2 * s]     = *(const bf16x8*)(xlT_bf + (size_t)(cg + m) * 2048 + k);
            xb[2 * s + 1] = *(const bf16x8*)(xlT_bf + (size_t)(cg + 16 + m) * 2048 + k);
        }

        // S phase: wave w computes cols 32w..32w+31
        #pragma unroll
        for (int s = 0; s < 2; ++s) {
            const int col = (w * 2 + s) * 16 + m;
            const unsigned short* ebj = emb_bf + (size_t)(j0 + col) * 64;
            bf16x8 b0 = *(const bf16x8*)(ebj + q * 8);
            bf16x8 b1 = *(const bf16x8*)(ebj + 32 + q * 8);
            f32x4 S = {0.f, 0.f, 0.f, 0.f};
            S = __builtin_amdgcn_mfma_f32_16x16x32_bf16(a0, b0, S, 0, 0, 0);
            S = __builtin_amdgcn_mfma_f32_16x16x32_bf16(a1, b1, S, 0, 0, 0);

            const float csqJ = sq[j0 + col];
            const int gcol = j0 + col;
            #pragma unroll
            for (int r = 0; r < 4; ++r) {
                int grow = i0 + q * 4 + r;
                float dist = 2.0f * S[r] - sqIr[r] - csqJ;
                float z = scale * dist + bias;
                float p = __builtin_amdgcn_rcpf(1.0f + __expf(-z));
                if (grow == gcol) p += 1.0f;
                dega[r] += p;
                P[(q * 4 + r) * LDP + col] = p;
            }
        }
        __syncthreads();

        // adjw store: 32 consecutive lanes x 16B = full 128B lines per instr
        {
            int row = t >> 5;            // 0..7
            int c0 = (t & 31) * 4;       // f32 col 0..124
            f32x4 v0 = *(const f32x4*)(&P[row * LDP + c0]);
            f32x4 v1 = *(const f32x4*)(&P[(row + 8) * LDP + c0]);
            *(f32x4*)(adjw + (size_t)(i0 + row) * 2048 + j0 + c0) = v0;
            *(f32x4*)(adjw + (size_t)(i0 + row + 8) * 2048 + j0 + c0) = v1;
        }

        // AX: acc += P(16x128) @ xlT (prefetched), K=128
        #pragma unroll
        for (int s = 0; s < 4; ++s) {
            float af[8];
            *(f32x4*)(&af[0]) = *(const f32x4*)(&P[m * LDP + s * 32 + q * 8]);
            *(f32x4*)(&af[4]) = *(const f32x4*)(&P[m * LDP + s * 32 + q * 8 + 4]);
            bf16x8 aa = pack_bf8(af);
            accO0 = __builtin_amdgcn_mfma_f32_16x16x32_bf16(aa, xb[2 * s], accO0, 0, 0, 0);
            accO1 = __builtin_amdgcn_mfma_f32_16x16x32_bf16(aa, xb[2 * s + 1], accO1, 0, 0, 0);
        }
    }

    // deg partial: reduce over m-lanes, combine 4 waves via LDS, plain store
    #pragma unroll
    for (int r = 0; r < 4; ++r) {
        float v = dega[r];
        v += __shfl_xor(v, 1);
        v += __shfl_xor(v, 2);
        v += __shfl_xor(v, 4);
        v += __shfl_xor(v, 8);
        if (m == 0) degS[w][q * 4 + r] = v;
    }
    __syncthreads();
    if (t < 16)
        degPart[bj * 2048 + i0 + t] =
            degS[0][t] + degS[1][t] + degS[2][t] + degS[3][t];

    // out partial: float2-packed full-line stores
    float2* opf2 = (float2*)outPart + ((size_t)bj * 128 + blockIdx.x) * 1024;
    #pragma unroll
    for (int r = 0; r < 4; ++r) {
        float2 pk;
        pk.x = accO0[r];
        pk.y = accO1[r];
        opf2[((q * 4 + r) * 4 + w) * 16 + m] = pk;
    }
}

// ---------------- Kernel 3: out = relu(sum_p outPart / sum_p degPart) ----------------
__global__ __launch_bounds__(256) void k3_fin(
    const float* __restrict__ outPart, const float* __restrict__ degPart,
    float* __restrict__ out)
{
    int gid = blockIdx.x * 256 + threadIdx.x;  // 131072 = 2048 rows * 64 (w,m)
    int i = gid >> 6;
    int wm = gid & 63;
    int w = wm >> 4, m = wm & 15;
    int tile = i >> 4, rit = i & 15;
    size_t base = (size_t)tile * 2048 + (size_t)((rit * 4 + w) * 16 + m) * 2;
    float s0 = 0.f, s1 = 0.f, d = 0.f;
    #pragma unroll
    for (int p = 0; p < 8; ++p) {
        const float* src = outPart + (size_t)p * 262144 + base;
        s0 += src[0];
        s1 += src[1];
        d += degPart[p * 2048 + i];
    }
    float dinv = 1.0f / d;
    out[(size_t)i * 128 + w * 32 + m] = fmaxf(s0 * dinv, 0.f);
    out[(size_t)i * 128 + w * 32 + 16 + m] = fmaxf(s1 * dinv, 0.f);
}

extern "C" void kernel_launch(void* const* d_in, const int* in_sizes, int n_in,
                              void* d_out, int out_size, void* d_ws, size_t ws_size,
                              hipStream_t stream) {
    const float* x     = (const float*)d_in[0];
    const float* W0    = (const float*)d_in[2];
    const float* b0    = (const float*)d_in[3];
    const float* W1    = (const float*)d_in[4];
    const float* b1    = (const float*)d_in[5];
    const float* W2    = (const float*)d_in[6];
    const float* b2    = (const float*)d_in[7];
    const float* temp  = (const float*)d_in[8];
    const float* theta = (const float*)d_in[9];

    char* ws = (char*)d_ws;
    unsigned short* emb_bf = (unsigned short*)(ws);            // 262144 B
    unsigned short* xlT_bf = (unsigned short*)(ws + 262144);   // 524288 B
    float* sq      = (float*)(ws + 786432);                    //   8192 B
    float* degPart = (float*)(ws + 794624);                    //  65536 B
    float* outPart = (float*)(ws + 860160);                    // 8 MiB
    unsigned short* W0P = (unsigned short*)(ws + 9248768);     // 65536 B
    unsigned short* W1P = (unsigned short*)(ws + 9314304);     // 32768 B
    unsigned short* W2P = (unsigned short*)(ws + 9347072);     // 32768 B

    float* out  = (float*)d_out;              // [2048*128]
    float* adjw = (float*)d_out + 262144;     // [2048*2048]

    k0_pack<<<32, 256, 0, stream>>>(W0, W1, W2, W0P, W1P, W2P);
    k1_mfma<<<128, 512, 0, stream>>>(x, W0P, b0, W1P, b1, W2P, b2,
                                     emb_bf, xlT_bf, sq);
    k2f<<<dim3(128, 8), 256, 0, stream>>>(emb_bf, xlT_bf, sq, temp, theta,
                                          adjw, outPart, degPart);
    k3_fin<<<512, 256, 0, stream>>>(outPart, degPart, out);
}